// Round 1
// baseline (370.073 us; speedup 1.0000x reference)
//
#include <hip/hip_runtime.h>

#define DIM 128

// ---------------- degree / normalization ----------------

__global__ __launch_bounds__(256) void k_deg(const int* __restrict__ ei,
                                             int* __restrict__ deg, int E, int N) {
    int e = blockIdx.x * 256 + threadIdx.x;
    if (e < E) {
        int d = ei[E + e];
        if ((unsigned)d < (unsigned)N) atomicAdd(&deg[d], 1);
    }
}

__global__ __launch_bounds__(256) void k_dis(const int* __restrict__ deg,
                                             float* __restrict__ dis, int N) {
    int i = blockIdx.x * 256 + threadIdx.x;
    if (i < N) dis[i] = rsqrtf((float)deg[i] + 1.0f);
}

// ---------------- CSR build: blocksum -> scan -> rowstart -> fill ----------------

__global__ __launch_bounds__(256) void k_blocksum(const int* __restrict__ deg,
                                                  int* __restrict__ bs, int N) {
    __shared__ int s[256];
    int t = threadIdx.x;
    int i = blockIdx.x * 256 + t;
    s[t] = (i < N) ? deg[i] : 0;
    __syncthreads();
    for (int off = 128; off > 0; off >>= 1) {
        if (t < off) s[t] += s[t + off];
        __syncthreads();
    }
    if (t == 0) bs[blockIdx.x] = s[0];
}

__global__ __launch_bounds__(256) void k_scanblocks(const int* __restrict__ bs,
                                                    int* __restrict__ boff, int nblk) {
    __shared__ int s[256];
    __shared__ int carry_s;
    int t = threadIdx.x;
    if (t == 0) carry_s = 0;
    __syncthreads();
    for (int base = 0; base < nblk; base += 256) {
        int i = base + t;
        int v = (i < nblk) ? bs[i] : 0;
        int carry = carry_s;
        s[t] = v;
        __syncthreads();
        for (int off = 1; off < 256; off <<= 1) {
            int tmp = (t >= off) ? s[t - off] : 0;
            __syncthreads();
            s[t] += tmp;
            __syncthreads();
        }
        int incl = s[t];
        if (i < nblk) boff[i] = carry + incl - v;  // exclusive prefix
        __syncthreads();
        if (t == 255) carry_s = carry + incl;
        __syncthreads();
    }
}

__global__ __launch_bounds__(256) void k_rowstart(const int* __restrict__ deg,
                                                  const int* __restrict__ boff,
                                                  int* __restrict__ rowstart, int N) {
    __shared__ int s[256];
    int t = threadIdx.x;
    int i = blockIdx.x * 256 + t;
    int v = (i < N) ? deg[i] : 0;
    s[t] = v;
    __syncthreads();
    for (int off = 1; off < 256; off <<= 1) {
        int tmp = (t >= off) ? s[t - off] : 0;
        __syncthreads();
        s[t] += tmp;
        __syncthreads();
    }
    if (i < N) rowstart[i] = boff[blockIdx.x] + s[t] - v;
}

__global__ __launch_bounds__(256) void k_fill(const int* __restrict__ ei,
                                              const int* __restrict__ rowstart,
                                              int* __restrict__ count,
                                              int* __restrict__ csr, int E, int N) {
    int e = blockIdx.x * 256 + threadIdx.x;
    if (e < E) {
        int sv = ei[e];
        int dv = ei[E + e];
        if ((unsigned)sv < (unsigned)N && (unsigned)dv < (unsigned)N) {
            int pos = rowstart[dv] + atomicAdd(&count[dv], 1);
            csr[pos] = sv;
        }
    }
}

// ---------------- fused GEMM: hn = (X @ W) * dis[row] ----------------
// 32 rows/block, 256 threads, 4x4 register tile/thread.
// X tile transposed into LDS [k][r]; W read via L1/L2 (64 KB, resident).

__global__ __launch_bounds__(256) void k_gemm(const float* __restrict__ X,
                                              const float* __restrict__ W,
                                              const float* __restrict__ dis,
                                              float* __restrict__ out, int N) {
    __shared__ float xs[DIM * 32];  // [k][r]
    int tid = threadIdx.x;
    int row0 = blockIdx.x * 32;
    // stage X transposed: 32x128 floats, 4 float4 per thread
#pragma unroll
    for (int i = tid * 4; i < 32 * DIM; i += 1024) {
        int r = i >> 7, k = i & 127;
        float4 v = make_float4(0.f, 0.f, 0.f, 0.f);
        int gr = row0 + r;
        if (gr < N) v = *(const float4*)(X + gr * DIM + k);
        xs[(k + 0) * 32 + r] = v.x;
        xs[(k + 1) * 32 + r] = v.y;
        xs[(k + 2) * 32 + r] = v.z;
        xs[(k + 3) * 32 + r] = v.w;
    }
    __syncthreads();

    int tx = tid & 31, ty = tid >> 5;
    int c0 = tx << 2, r0 = ty << 2;
    float acc[4][4];
#pragma unroll
    for (int i = 0; i < 4; ++i)
#pragma unroll
        for (int j = 0; j < 4; ++j) acc[i][j] = 0.f;

    const float* Wp = W + c0;
#pragma unroll 8
    for (int k = 0; k < DIM; ++k) {
        float4 wv = *(const float4*)(Wp + k * DIM);
        float4 xv = *(const float4*)(xs + k * 32 + r0);
        acc[0][0] += xv.x * wv.x; acc[0][1] += xv.x * wv.y; acc[0][2] += xv.x * wv.z; acc[0][3] += xv.x * wv.w;
        acc[1][0] += xv.y * wv.x; acc[1][1] += xv.y * wv.y; acc[1][2] += xv.y * wv.z; acc[1][3] += xv.y * wv.w;
        acc[2][0] += xv.z * wv.x; acc[2][1] += xv.z * wv.y; acc[2][2] += xv.z * wv.z; acc[2][3] += xv.z * wv.w;
        acc[3][0] += xv.w * wv.x; acc[3][1] += xv.w * wv.y; acc[3][2] += xv.w * wv.z; acc[3][3] += xv.w * wv.w;
    }

#pragma unroll
    for (int i = 0; i < 4; ++i) {
        int gr = row0 + r0 + i;
        if (gr < N) {
            float sc = dis[gr];
            float4 o = make_float4(acc[i][0] * sc, acc[i][1] * sc, acc[i][2] * sc, acc[i][3] * sc);
            *(float4*)(out + gr * DIM + c0) = o;
        }
    }
}

// ---------------- aggregate: out[v] = dis[v]*(hn[v] + sum_in hn[src]) + b ----------------
// one wave per node; half-wave handles one edge via float4 (2 edges per iter, 4 with unroll)

__global__ __launch_bounds__(256) void k_agg(const float* __restrict__ hn,
                                             const int* __restrict__ csr,
                                             const int* __restrict__ rowstart,
                                             const int* __restrict__ deg,
                                             const float* __restrict__ dis,
                                             const float* __restrict__ bias,
                                             float* __restrict__ out, int N, int do_relu) {
    int t = threadIdx.x;
    int wave = t >> 6, lane = t & 63;
    int node = blockIdx.x * 4 + wave;
    if (node >= N) return;
    int beg = rowstart[node];
    int end = beg + deg[node];
    int half = lane >> 5;
    int c4 = (lane & 31) << 2;

    float4 acc = make_float4(0.f, 0.f, 0.f, 0.f);
    for (int e0 = beg; e0 < end; e0 += 4) {
        int eA = e0 + half;
        int eB = e0 + 2 + half;
        int sA = (eA < end) ? csr[eA] : -1;
        int sB = (eB < end) ? csr[eB] : -1;
        float4 vA = make_float4(0.f, 0.f, 0.f, 0.f);
        float4 vB = make_float4(0.f, 0.f, 0.f, 0.f);
        if (sA >= 0) vA = *(const float4*)(hn + sA * DIM + c4);
        if (sB >= 0) vB = *(const float4*)(hn + sB * DIM + c4);
        acc.x += vA.x + vB.x;
        acc.y += vA.y + vB.y;
        acc.z += vA.z + vB.z;
        acc.w += vA.w + vB.w;
    }
    // combine upper half into lower half
    float ox = acc.x + __shfl(acc.x, lane + 32, 64);
    float oy = acc.y + __shfl(acc.y, lane + 32, 64);
    float oz = acc.z + __shfl(acc.z, lane + 32, 64);
    float ow = acc.w + __shfl(acc.w, lane + 32, 64);

    if (half == 0) {
        float4 selfv = *(const float4*)(hn + node * DIM + c4);
        float sc = dis[node];
        float4 bv = *(const float4*)(bias + c4);
        float4 o;
        o.x = (ox + selfv.x) * sc + bv.x;
        o.y = (oy + selfv.y) * sc + bv.y;
        o.z = (oz + selfv.z) * sc + bv.z;
        o.w = (ow + selfv.w) * sc + bv.w;
        if (do_relu) {
            o.x = fmaxf(o.x, 0.f);
            o.y = fmaxf(o.y, 0.f);
            o.z = fmaxf(o.z, 0.f);
            o.w = fmaxf(o.w, 0.f);
        }
        *(float4*)(out + node * DIM + c4) = o;
    }
}

// ---------------- launch ----------------

extern "C" void kernel_launch(void* const* d_in, const int* in_sizes, int n_in,
                              void* d_out, int out_size, void* d_ws, size_t ws_size,
                              hipStream_t stream) {
    const int* ei = (const int*)d_in[0];
    const float* emb = (const float*)d_in[1];
    const float* W1 = (const float*)d_in[2];
    const float* b1 = (const float*)d_in[3];
    const float* W2 = (const float*)d_in[4];
    const float* b2 = (const float*)d_in[5];
    float* out = (float*)d_out;

    const int E = in_sizes[0] / 2;
    const int N = in_sizes[1] / DIM;
    const int nblk = (N + 255) / 256;

    char* p = (char*)d_ws;
    auto alloc = [&](size_t bytes) -> char* {
        char* r = p;
        p += (bytes + 255) & ~(size_t)255;
        return r;
    };
    int* deg      = (int*)alloc((size_t)N * 4);
    int* count    = (int*)alloc((size_t)N * 4);
    float* dis    = (float*)alloc((size_t)N * 4);
    int* rowstart = (int*)alloc((size_t)N * 4);
    int* bs       = (int*)alloc((size_t)nblk * 4);
    int* boff     = (int*)alloc((size_t)nblk * 4);
    int* csr      = (int*)alloc((size_t)E * 4);
    float* hn     = (float*)alloc((size_t)N * DIM * 4);
    float* x2     = (float*)alloc((size_t)N * DIM * 4);

    hipMemsetAsync(deg, 0, (size_t)N * 4, stream);
    hipMemsetAsync(count, 0, (size_t)N * 4, stream);

    k_deg<<<(E + 255) / 256, 256, 0, stream>>>(ei, deg, E, N);
    k_dis<<<(N + 255) / 256, 256, 0, stream>>>(deg, dis, N);
    k_blocksum<<<nblk, 256, 0, stream>>>(deg, bs, N);
    k_scanblocks<<<1, 256, 0, stream>>>(bs, boff, nblk);
    k_rowstart<<<nblk, 256, 0, stream>>>(deg, boff, rowstart, N);
    k_fill<<<(E + 255) / 256, 256, 0, stream>>>(ei, rowstart, count, csr, E, N);

    // layer 1: hn1 = (emb @ W1) * dis ; x2 = relu(dis*(hn1 + sum_in hn1[src]) + b1)
    k_gemm<<<(N + 31) / 32, 256, 0, stream>>>(emb, W1, dis, hn, N);
    k_agg<<<(N + 3) / 4, 256, 0, stream>>>(hn, csr, rowstart, deg, dis, b1, x2, N, 1);

    // layer 2: hn2 = (x2 @ W2) * dis ; out = dis*(hn2 + sum_in hn2[src]) + b2
    k_gemm<<<(N + 31) / 32, 256, 0, stream>>>(x2, W2, dis, hn, N);
    k_agg<<<(N + 3) / 4, 256, 0, stream>>>(hn, csr, rowstart, deg, dis, b2, out, N, 0);
}

// Round 2
// 349.796 us; speedup vs baseline: 1.0580x; 1.0580x over previous
//
#include <hip/hip_runtime.h>
#include <hip/hip_fp16.h>

#define DIM 128

// ---------------- degree ----------------

__global__ __launch_bounds__(256) void k_deg(const int* __restrict__ ei,
                                             int* __restrict__ deg, int E, int N) {
    int e = blockIdx.x * 256 + threadIdx.x;
    if (e < E) {
        int d = ei[E + e];
        if ((unsigned)d < (unsigned)N) atomicAdd(&deg[d], 1);
    }
}

// ---------------- CSR build: blocksum(+dis) -> scan -> rowstart(+count=0) -> fill ----------------

__global__ __launch_bounds__(256) void k_blocksum_dis(const int* __restrict__ deg,
                                                      float* __restrict__ dis,
                                                      int* __restrict__ bs, int N) {
    __shared__ int s[256];
    int t = threadIdx.x;
    int i = blockIdx.x * 256 + t;
    int v = (i < N) ? deg[i] : 0;
    if (i < N) dis[i] = rsqrtf((float)v + 1.0f);
    s[t] = v;
    __syncthreads();
    for (int off = 128; off > 0; off >>= 1) {
        if (t < off) s[t] += s[t + off];
        __syncthreads();
    }
    if (t == 0) bs[blockIdx.x] = s[0];
}

__global__ __launch_bounds__(256) void k_scanblocks(const int* __restrict__ bs,
                                                    int* __restrict__ boff, int nblk) {
    __shared__ int s[256];
    __shared__ int carry_s;
    int t = threadIdx.x;
    if (t == 0) carry_s = 0;
    __syncthreads();
    for (int base = 0; base < nblk; base += 256) {
        int i = base + t;
        int v = (i < nblk) ? bs[i] : 0;
        int carry = carry_s;
        s[t] = v;
        __syncthreads();
        for (int off = 1; off < 256; off <<= 1) {
            int tmp = (t >= off) ? s[t - off] : 0;
            __syncthreads();
            s[t] += tmp;
            __syncthreads();
        }
        int incl = s[t];
        if (i < nblk) boff[i] = carry + incl - v;  // exclusive prefix
        __syncthreads();
        if (t == 255) carry_s = carry + incl;
        __syncthreads();
    }
}

__global__ __launch_bounds__(256) void k_rowstart(const int* __restrict__ deg,
                                                  const int* __restrict__ boff,
                                                  int* __restrict__ rowstart,
                                                  int* __restrict__ count, int N) {
    __shared__ int s[256];
    int t = threadIdx.x;
    int i = blockIdx.x * 256 + t;
    int v = (i < N) ? deg[i] : 0;
    s[t] = v;
    __syncthreads();
    for (int off = 1; off < 256; off <<= 1) {
        int tmp = (t >= off) ? s[t - off] : 0;
        __syncthreads();
        s[t] += tmp;
        __syncthreads();
    }
    if (i < N) {
        rowstart[i] = boff[blockIdx.x] + s[t] - v;
        count[i] = 0;
    }
}

__global__ __launch_bounds__(256) void k_fill(const int* __restrict__ ei,
                                              const int* __restrict__ rowstart,
                                              int* __restrict__ count,
                                              int* __restrict__ csr, int E, int N) {
    int e = blockIdx.x * 256 + threadIdx.x;
    if (e < E) {
        int sv = ei[e];
        int dv = ei[E + e];
        if ((unsigned)sv < (unsigned)N && (unsigned)dv < (unsigned)N) {
            int pos = rowstart[dv] + atomicAdd(&count[dv], 1);
            csr[pos] = sv;
        }
    }
}

// ---------------- fused GEMM: hn = fp16((X @ W) * dis[row]) ----------------
// 32 rows/block, 256 threads, 4x4 register tile/thread.
// X tile row-major in LDS (stride 132: conflict-minimal b128 writes, broadcast b128 reads).

template <typename T>
__global__ __launch_bounds__(256) void k_gemm(const T* __restrict__ X,
                                              const float* __restrict__ W,
                                              const float* __restrict__ dis,
                                              __half* __restrict__ out, int N) {
    __shared__ float xs[32 * 132];
    int tid = threadIdx.x;
    int row0 = blockIdx.x * 32;

    if constexpr (sizeof(T) == 4) {
        // fp32 input: 4096 floats, 4 float4 per thread
        for (int i = tid * 4; i < 32 * DIM; i += 1024) {
            int r = i >> 7, k = i & 127;
            int gr = row0 + r;
            float4 v = make_float4(0.f, 0.f, 0.f, 0.f);
            if (gr < N) v = *(const float4*)((const float*)X + (size_t)gr * DIM + k);
            *(float4*)(xs + r * 132 + k) = v;
        }
    } else {
        // fp16 input: 4096 halfs, 8 halfs (uint4) per thread per iter, 2 iters
        for (int i = tid * 8; i < 32 * DIM; i += 2048) {
            int r = i >> 7, k = i & 127;
            int gr = row0 + r;
            uint4 v = make_uint4(0u, 0u, 0u, 0u);
            if (gr < N) v = *(const uint4*)((const __half*)X + (size_t)gr * DIM + k);
            const __half2* h = (const __half2*)&v;
            float2 f0 = __half22float2(h[0]);
            float2 f1 = __half22float2(h[1]);
            float2 f2 = __half22float2(h[2]);
            float2 f3 = __half22float2(h[3]);
            *(float4*)(xs + r * 132 + k)     = make_float4(f0.x, f0.y, f1.x, f1.y);
            *(float4*)(xs + r * 132 + k + 4) = make_float4(f2.x, f2.y, f3.x, f3.y);
        }
    }
    __syncthreads();

    int tx = tid & 31, ty = tid >> 5;
    int c0 = tx << 2, r0 = ty << 2;
    float acc[4][4];
#pragma unroll
    for (int i = 0; i < 4; ++i)
#pragma unroll
        for (int j = 0; j < 4; ++j) acc[i][j] = 0.f;

    const float* Wp = W + c0;
#pragma unroll 4
    for (int k = 0; k < DIM; k += 4) {
        float4 w0 = *(const float4*)(Wp + (size_t)(k + 0) * DIM);
        float4 w1 = *(const float4*)(Wp + (size_t)(k + 1) * DIM);
        float4 w2 = *(const float4*)(Wp + (size_t)(k + 2) * DIM);
        float4 w3 = *(const float4*)(Wp + (size_t)(k + 3) * DIM);
        float4 x0 = *(const float4*)(xs + (r0 + 0) * 132 + k);
        float4 x1 = *(const float4*)(xs + (r0 + 1) * 132 + k);
        float4 x2 = *(const float4*)(xs + (r0 + 2) * 132 + k);
        float4 x3 = *(const float4*)(xs + (r0 + 3) * 132 + k);
        acc[0][0] += x0.x*w0.x + x0.y*w1.x + x0.z*w2.x + x0.w*w3.x;
        acc[0][1] += x0.x*w0.y + x0.y*w1.y + x0.z*w2.y + x0.w*w3.y;
        acc[0][2] += x0.x*w0.z + x0.y*w1.z + x0.z*w2.z + x0.w*w3.z;
        acc[0][3] += x0.x*w0.w + x0.y*w1.w + x0.z*w2.w + x0.w*w3.w;
        acc[1][0] += x1.x*w0.x + x1.y*w1.x + x1.z*w2.x + x1.w*w3.x;
        acc[1][1] += x1.x*w0.y + x1.y*w1.y + x1.z*w2.y + x1.w*w3.y;
        acc[1][2] += x1.x*w0.z + x1.y*w1.z + x1.z*w2.z + x1.w*w3.z;
        acc[1][3] += x1.x*w0.w + x1.y*w1.w + x1.z*w2.w + x1.w*w3.w;
        acc[2][0] += x2.x*w0.x + x2.y*w1.x + x2.z*w2.x + x2.w*w3.x;
        acc[2][1] += x2.x*w0.y + x2.y*w1.y + x2.z*w2.y + x2.w*w3.y;
        acc[2][2] += x2.x*w0.z + x2.y*w1.z + x2.z*w2.z + x2.w*w3.z;
        acc[2][3] += x2.x*w0.w + x2.y*w1.w + x2.z*w2.w + x2.w*w3.w;
        acc[3][0] += x3.x*w0.x + x3.y*w1.x + x3.z*w2.x + x3.w*w3.x;
        acc[3][1] += x3.x*w0.y + x3.y*w1.y + x3.z*w2.y + x3.w*w3.y;
        acc[3][2] += x3.x*w0.z + x3.y*w1.z + x3.z*w2.z + x3.w*w3.z;
        acc[3][3] += x3.x*w0.w + x3.y*w1.w + x3.z*w2.w + x3.w*w3.w;
    }

#pragma unroll
    for (int i = 0; i < 4; ++i) {
        int gr = row0 + r0 + i;
        if (gr < N) {
            float sc = dis[gr];
            __half2 h01 = __floats2half2_rn(acc[i][0] * sc, acc[i][1] * sc);
            __half2 h23 = __floats2half2_rn(acc[i][2] * sc, acc[i][3] * sc);
            union { __half2 h[2]; float2 f; } u;
            u.h[0] = h01; u.h[1] = h23;
            *(float2*)(out + (size_t)gr * DIM + c0) = u.f;
        }
    }
}

// ---------------- aggregate: out[v] = dis[v]*(hn[v] + sum_in hn[src]) + b ----------------
// one wave per node; 4 slots of 16 lanes, each slot loads one fp16 row (256B) per uint4;
// 8 edges in flight per wave iteration.

__global__ __launch_bounds__(256) void k_agg(const __half* __restrict__ hn,
                                             const int* __restrict__ csr,
                                             const int* __restrict__ rowstart,
                                             const int* __restrict__ deg,
                                             const float* __restrict__ dis,
                                             const float* __restrict__ bias,
                                             float* __restrict__ outf,
                                             __half* __restrict__ outh,
                                             int N, int do_relu) {
    int t = threadIdx.x;
    int wave = t >> 6, lane = t & 63;
    int node = blockIdx.x * 4 + wave;
    if (node >= N) return;
    int beg = rowstart[node];
    int end = beg + deg[node];
    int slot = lane >> 4;
    int c8 = (lane & 15) << 3;  // half-channel index, 8 per lane

    float acc[8];
#pragma unroll
    for (int j = 0; j < 8; ++j) acc[j] = 0.f;

    const uint4 z4 = make_uint4(0u, 0u, 0u, 0u);
    for (int e0 = beg; e0 < end; e0 += 8) {
        int eA = e0 + slot;
        int eB = e0 + 4 + slot;
        int sA = (eA < end) ? csr[eA] : -1;
        int sB = (eB < end) ? csr[eB] : -1;
        uint4 va = (sA >= 0) ? *(const uint4*)(hn + (size_t)sA * DIM + c8) : z4;
        uint4 vb = (sB >= 0) ? *(const uint4*)(hn + (size_t)sB * DIM + c8) : z4;
        const __half2* ha = (const __half2*)&va;
        const __half2* hb = (const __half2*)&vb;
#pragma unroll
        for (int j = 0; j < 4; ++j) {
            float2 fa = __half22float2(ha[j]);
            float2 fb = __half22float2(hb[j]);
            acc[2 * j]     += fa.x + fb.x;
            acc[2 * j + 1] += fa.y + fb.y;
        }
    }

#pragma unroll
    for (int j = 0; j < 8; ++j) {
        acc[j] += __shfl_xor(acc[j], 16, 64);
        acc[j] += __shfl_xor(acc[j], 32, 64);
    }

    if (slot == 0) {
        uint4 sv = *(const uint4*)(hn + (size_t)node * DIM + c8);
        const __half2* hs = (const __half2*)&sv;
        float sc = dis[node];
        float4 bv0 = *(const float4*)(bias + c8);
        float4 bv1 = *(const float4*)(bias + c8 + 4);
        float bb[8] = {bv0.x, bv0.y, bv0.z, bv0.w, bv1.x, bv1.y, bv1.z, bv1.w};
        float o[8];
#pragma unroll
        for (int j = 0; j < 4; ++j) {
            float2 fs = __half22float2(hs[j]);
            o[2 * j]     = (acc[2 * j]     + fs.x) * sc + bb[2 * j];
            o[2 * j + 1] = (acc[2 * j + 1] + fs.y) * sc + bb[2 * j + 1];
        }
        if (do_relu) {
            // layer-1 path: relu + fp16 store (feeds next GEMM)
            __half2 p0 = __floats2half2_rn(fmaxf(o[0], 0.f), fmaxf(o[1], 0.f));
            __half2 p1 = __floats2half2_rn(fmaxf(o[2], 0.f), fmaxf(o[3], 0.f));
            __half2 p2 = __floats2half2_rn(fmaxf(o[4], 0.f), fmaxf(o[5], 0.f));
            __half2 p3 = __floats2half2_rn(fmaxf(o[6], 0.f), fmaxf(o[7], 0.f));
            union { __half2 h[4]; uint4 u; } pu;
            pu.h[0] = p0; pu.h[1] = p1; pu.h[2] = p2; pu.h[3] = p3;
            *(uint4*)(outh + (size_t)node * DIM + c8) = pu.u;
        } else {
            // layer-2 path: fp32 store to d_out
            *(float4*)(outf + (size_t)node * DIM + c8) = make_float4(o[0], o[1], o[2], o[3]);
            *(float4*)(outf + (size_t)node * DIM + c8 + 4) = make_float4(o[4], o[5], o[6], o[7]);
        }
    }
}

// ---------------- launch ----------------

extern "C" void kernel_launch(void* const* d_in, const int* in_sizes, int n_in,
                              void* d_out, int out_size, void* d_ws, size_t ws_size,
                              hipStream_t stream) {
    const int* ei = (const int*)d_in[0];
    const float* emb = (const float*)d_in[1];
    const float* W1 = (const float*)d_in[2];
    const float* b1 = (const float*)d_in[3];
    const float* W2 = (const float*)d_in[4];
    const float* b2 = (const float*)d_in[5];
    float* out = (float*)d_out;

    const int E = in_sizes[0] / 2;
    const int N = in_sizes[1] / DIM;
    const int nblk = (N + 255) / 256;

    char* p = (char*)d_ws;
    auto alloc = [&](size_t bytes) -> char* {
        char* r = p;
        p += (bytes + 255) & ~(size_t)255;
        return r;
    };
    int* deg      = (int*)alloc((size_t)N * 4);
    int* count    = (int*)alloc((size_t)N * 4);
    float* dis    = (float*)alloc((size_t)N * 4);
    int* rowstart = (int*)alloc((size_t)N * 4);
    int* bs       = (int*)alloc((size_t)nblk * 4);
    int* boff     = (int*)alloc((size_t)nblk * 4);
    int* csr      = (int*)alloc((size_t)E * 4);
    __half* hn    = (__half*)alloc((size_t)N * DIM * 2);
    __half* x2    = (__half*)alloc((size_t)N * DIM * 2);

    hipMemsetAsync(deg, 0, (size_t)N * 4, stream);

    k_deg<<<(E + 255) / 256, 256, 0, stream>>>(ei, deg, E, N);
    k_blocksum_dis<<<nblk, 256, 0, stream>>>(deg, dis, bs, N);
    k_scanblocks<<<1, 256, 0, stream>>>(bs, boff, nblk);
    k_rowstart<<<nblk, 256, 0, stream>>>(deg, boff, rowstart, count, N);
    k_fill<<<(E + 255) / 256, 256, 0, stream>>>(ei, rowstart, count, csr, E, N);

    // layer 1: hn = fp16((emb @ W1) * dis) ; x2 = fp16(relu(dis*(hn + sum) + b1))
    k_gemm<float><<<(N + 31) / 32, 256, 0, stream>>>(emb, W1, dis, hn, N);
    k_agg<<<(N + 3) / 4, 256, 0, stream>>>(hn, csr, rowstart, deg, dis, b1, nullptr, x2, N, 1);

    // layer 2: hn = fp16((x2 @ W2) * dis) ; out = dis*(hn + sum) + b2
    k_gemm<__half><<<(N + 31) / 32, 256, 0, stream>>>(x2, W2, dis, hn, N);
    k_agg<<<(N + 3) / 4, 256, 0, stream>>>(hn, csr, rowstart, deg, dis, b2, out, nullptr, N, 0);
}